// Round 16
// baseline (104.585 us; speedup 1.0000x reference)
//
#include <hip/hip_runtime.h>
#include <cstdint>
#include <cstddef>

// ---------------- problem constants ----------------
#define NB    32          // batch
#define CI    128         // in channels
#define CO    256         // out channels
#define HW_   56          // spatial
#define HP    58          // padded spatial
#define KTOT  1152        // 128*9 reduction
#define NKT   36          // K-tiles of 32
#define MTOT  (NB * HW_ * HW_)   // 100352 output pixels

static constexpr size_t XP_ELEMS = (size_t)NB * HP * HP * CI;   // 13,776,896
static constexpr size_t WT_ELEMS = (size_t)CO * KTOT;           // 294,912
static constexpr size_t XP_BYTES = XP_ELEMS * 2;
static constexpr size_t WT_BYTES = WT_ELEMS * 2;

typedef __attribute__((ext_vector_type(8)))  short bf16x8;
typedef __attribute__((ext_vector_type(16))) float f32x16;

__device__ __forceinline__ short f32_to_bf16(float f) {
  uint32_t u = __float_as_uint(f);
  uint32_t r = (u + 0x7FFFu + ((u >> 16) & 1u)) >> 16;
  return (short)r;
}

typedef __attribute__((address_space(3))) void       lds_void;
typedef const __attribute__((address_space(1))) void gbl_void;

__device__ __forceinline__ void gload16(const void* g, void* l) {
  // dest = wave-uniform LDS base; HW writes lane's 16B at base + lane*16
  __builtin_amdgcn_global_load_lds((gbl_void*)g, (lds_void*)l, 16, 0, 0);
}

// ---- pre-pass: x NCHW f32 -> padded NHWC bf16; wt OIHW -> [o][kh][kw][c] bf16 ----
// (verified-correct R4 version)
__global__ void pad_convert(const float* __restrict__ x, short* __restrict__ xp,
                            const float* __restrict__ wt, short* __restrict__ wbT) {
  __shared__ float lds[CI][57];
  const int blk = blockIdx.x;    // NB*HP = 1856
  const int hp  = blk % HP;
  const int nb  = blk / HP;
  const int tid = threadIdx.x;   // 256

  if (blk < 1152) {              // 1152*256 == WT_ELEMS (scalar per thread)
    int idx = blk * 256 + tid;
    int c  = idx & 127;
    int t  = idx >> 7;          // o*9 + kh*3 + kw
    int kw = t % 3;  int t2 = t / 3;
    int kh = t2 % 3; int o  = t2 / 3;
    wbT[idx] = f32_to_bf16(wt[(((size_t)o * CI + c) * 3 + kh) * 3 + kw]);
  }

  const bool interior = (hp >= 1 && hp <= HW_);
  if (interior) {
    const float* src = x + (size_t)nb * CI * HW_ * HW_ + (size_t)(hp - 1) * HW_;
    for (int t = tid; t < CI * HW_; t += 256) {
      int c = t / HW_, w = t - (t / HW_) * HW_;
      lds[c][w] = src[(size_t)c * HW_ * HW_ + w];
    }
  }
  __syncthreads();
  short* dst = xp + (size_t)(nb * HP + hp) * HP * CI;
  for (int t = tid; t < HP * CI / 4; t += 256) {
    const int wp = t >> 5;
    const int c4 = (t & 31) * 4;
    short4 s;
    if (interior && wp >= 1 && wp <= HW_) {
      s.x = f32_to_bf16(lds[c4 + 0][wp - 1]);
      s.y = f32_to_bf16(lds[c4 + 1][wp - 1]);
      s.z = f32_to_bf16(lds[c4 + 2][wp - 1]);
      s.w = f32_to_bf16(lds[c4 + 3][wp - 1]);
    } else {
      s.x = s.y = s.z = s.w = 0;
    }
    *(short4*)(dst + t * 4) = s;
  }
}

// scalar byte offset into an xp pixel row for K-tile u (tap + channel-quarter)
__device__ __forceinline__ int stage_aoff(int u) {
  const int tap = u >> 2;            // 0..8
  const int cq  = u & 3;             // channel quarter (32 ch)
  const int kh  = tap / 3, kw = tap - kh * 3;
  return ((kh * HP + kw) * CI + cq * 32) * 2;
}

// ---------------- main: implicit GEMM, 256x128 tile, BK=32, 4 waves ----------------
// R16 = R4's twice-passed skeleton (counted vmcnt(6) ledger, 3 x 24KB buffers,
// 2 blocks/CU, same staging swizzle) with ONE variable changed: 32x32x16 MFMA
// replaces 16x16x32 (3967 vs 3378 FLOP/cyc -> -17% MFMA-pipe time; 16 vs 32
// MFMA instrs per wave per K-tile -> half the matrix issue slots).
// Frag reads (32 rows x 2 k-pieces per frag): row = base32 + (l&31), logical
// piece q = kk*2 + (l>>5); LDS piece = q ^ ((row>>1)&3) = q ^ ((l>>1)&3)
// (base32 mult of 32). Staging holds slot (row,pc) = global pc^((row>>1)&3)
// -- identical invariant to R4, so STAGE is verbatim.
// Epilogue 32x32 C/D mapping verified on-device in R6 (passed, absmax 1.0):
// col = lane&31 (m), row = (reg&3) + 8*(reg>>2) + 4*(lane>>5) (oc).
__global__ __launch_bounds__(256, 2) void conv_gemm(
    const short* __restrict__ xp, const short* __restrict__ wbT,
    const float* __restrict__ bias, float* __restrict__ out) {
  __shared__ __align__(16) char lds_[3 * 24576];

  const int tid = threadIdx.x;     // 256
  const int l   = tid & 63;
  const int wv  = tid >> 6;        // 0..3
  const int wm  = wv >> 1;         // 0..1  (m half: 128 rows)
  const int wn  = wv & 1;          // 0..1  (oc half: 64 cols)

  // grid 784 = 8 XCDs x 98; chunked bijective swizzle, nt inner (A reuse in L2)
  const int bid = blockIdx.x;
  const int lin = (bid & 7) * 98 + (bid >> 3);
  const int mt  = lin >> 1;
  const int nt  = lin & 1;

  // ---- staging source pointers (pre-swizzled per rule #21; R4 verbatim) ----
  const int pcs  = (((l & 3) ^ ((l >> 3) & 3)) << 4);
  const int srow = 16 * wv + (l >> 2);                 // 0..63 per gload group
  const char *aSrc0, *aSrc1, *aSrc2, *aSrc3;
  {
#pragma unroll
    for (int g = 0; g < 4; ++g) {
      int m  = mt * 256 + 64 * g + srow;
      int nb = m / 3136, hw = m - nb * 3136;
      int h = hw / HW_, w = hw - (hw / HW_) * HW_;
      const char* p = (const char*)xp + ((size_t)((nb * HP + h) * HP + w) * CI) * 2 + pcs;
      if (g == 0) aSrc0 = p; else if (g == 1) aSrc1 = p;
      else if (g == 2) aSrc2 = p; else aSrc3 = p;
    }
  }
  const char* bSrc0 = (const char*)wbT + (size_t)(nt * 128 +      srow) * KTOT * 2 + pcs;
  const char* bSrc1 = (const char*)wbT + (size_t)(nt * 128 + 64 + srow) * KTOT * 2 + pcs;

  // ---- 32x32 frag read offsets (swizzled; same XOR family as R4) ----
  const int l31  = l & 31;
  int kswz[2];
#pragma unroll
  for (int kk = 0; kk < 2; ++kk)
    kswz[kk] = (((kk * 2 + (l >> 5)) ^ ((l >> 1) & 3)) << 4);
  const int raOff = (wm * 128 + l31) * 64;            // + g*2048, g=0..3
  const int rbOff = (wn * 64 + l31) * 64;             // + h*2048 (B region +16384)

  char* B0 = lds_;
  char* B1 = lds_ + 24576;
  char* B2 = lds_ + 49152;

#define STAGE(U, BUF)                                                        \
  {                                                                          \
    const int ao_ = stage_aoff(U);                                           \
    const int bo_ = (U) * 64;                                                \
    gload16(aSrc0 + ao_, (BUF) +         wv * 1024);                         \
    gload16(aSrc1 + ao_, (BUF) +  4096 + wv * 1024);                         \
    gload16(aSrc2 + ao_, (BUF) +  8192 + wv * 1024);                         \
    gload16(aSrc3 + ao_, (BUF) + 12288 + wv * 1024);                         \
    gload16(bSrc0 + bo_, (BUF) + 16384 + wv * 1024);                         \
    gload16(bSrc1 + bo_, (BUF) + 20480 + wv * 1024);                         \
  }

  f32x16 acc[4][2];
#pragma unroll
  for (int g = 0; g < 4; ++g)
#pragma unroll
    for (int h = 0; h < 2; ++h)
#pragma unroll
      for (int e = 0; e < 16; ++e) acc[g][h][e] = 0.f;

  // ---- prologue: stage tiles 0,1; confirm tile 0 ----
  STAGE(0, B0)
  STAGE(1, B1)
  asm volatile("s_waitcnt vmcnt(6)" ::: "memory");   // tile 0 landed
  __builtin_amdgcn_s_barrier();
  __builtin_amdgcn_sched_barrier(0);

#define TILE_BODY(V, CUR, STG)                                               \
  {                                                                          \
    const int v_ = (V);                                                      \
    if (v_ + 2 < NKT) STAGE(v_ + 2, STG)                                     \
    bf16x8 af[4][2], bf[2][2];                                               \
    _Pragma("unroll") for (int g = 0; g < 4; ++g)                            \
      _Pragma("unroll") for (int kk = 0; kk < 2; ++kk)                       \
        af[g][kk] = *(const bf16x8*)((CUR) + raOff + g * 2048 + kswz[kk]);   \
    _Pragma("unroll") for (int h = 0; h < 2; ++h)                            \
      _Pragma("unroll") for (int kk = 0; kk < 2; ++kk)                       \
        bf[h][kk] = *(const bf16x8*)((CUR) + 16384 + rbOff + h * 2048 + kswz[kk]); \
    __builtin_amdgcn_s_setprio(1);                                           \
    _Pragma("unroll") for (int kk = 0; kk < 2; ++kk)                         \
      _Pragma("unroll") for (int g = 0; g < 4; ++g)                          \
        _Pragma("unroll") for (int h = 0; h < 2; ++h)                        \
          acc[g][h] = __builtin_amdgcn_mfma_f32_32x32x16_bf16(               \
              bf[h][kk], af[g][kk], acc[g][h], 0, 0, 0);                     \
    __builtin_amdgcn_s_setprio(0);                                           \
    if (v_ < NKT - 1) {                                                      \
      if (v_ == NKT - 2) { asm volatile("s_waitcnt vmcnt(0)" ::: "memory"); }\
      else               { asm volatile("s_waitcnt vmcnt(6)" ::: "memory"); }\
      __builtin_amdgcn_s_barrier();                                          \
      __builtin_amdgcn_sched_barrier(0);                                     \
    }                                                                        \
  }

  for (int v3 = 0; v3 < NKT; v3 += 3) {
    TILE_BODY(v3 + 0, B0, B2)   // tile v reads buf v%3, stages v+2 into (v+2)%3
    TILE_BODY(v3 + 1, B1, B0)
    TILE_BODY(v3 + 2, B2, B1)
  }
#undef TILE_BODY
#undef STAGE

  // ---- epilogue: 32x32 C/D (swapped operands): D row = oc, col = m ----
  //      (verified on-device in R6: col = lane&31, row = (reg&3)+8*(reg>>2)+4*(lane>>5))
  const int ocB = nt * 128 + wn * 64 + 4 * (l >> 5);
  float bb[2][16];
#pragma unroll
  for (int h = 0; h < 2; ++h)
#pragma unroll
    for (int q = 0; q < 4; ++q)
#pragma unroll
      for (int j = 0; j < 4; ++j)
        bb[h][q * 4 + j] = bias[ocB + h * 32 + q * 8 + j];
#pragma unroll
  for (int g = 0; g < 4; ++g) {
    const int mB = mt * 256 + wm * 128 + g * 32;   // 32-aligned: never crosses 3136
    const int nb = mB / 3136;
    const int hw = mB - nb * 3136 + l31;
    float* op = out + (size_t)nb * CO * 3136 + hw;
#pragma unroll
    for (int h = 0; h < 2; ++h)
#pragma unroll
      for (int q = 0; q < 4; ++q)
#pragma unroll
        for (int j = 0; j < 4; ++j) {
          const int oc = ocB + h * 32 + q * 8 + j;
          op[(size_t)oc * 3136] = acc[g][h][q * 4 + j] + bb[h][q * 4 + j];
        }
  }
}

// ---------------- fallback (ws too small): naive direct conv ----------------
__global__ void conv_naive(const float* __restrict__ x, const float* __restrict__ wt,
                           const float* __restrict__ bias, float* __restrict__ out) {
  const int idx = blockIdx.x * 256 + threadIdx.x;
  if (idx >= NB * CO * 3136) return;
  const int w  = idx % HW_;
  const int h  = (idx / HW_) % HW_;
  const int oc = (idx / 3136) % CO;
  const int nb = idx / (3136 * CO);
  float s = bias[oc];
  for (int c = 0; c < CI; ++c)
    for (int kh = 0; kh < 3; ++kh) {
      const int ih = h + kh - 1;
      if (ih < 0 || ih >= HW_) continue;
      for (int kw = 0; kw < 3; ++kw) {
        const int iw = w + kw - 1;
        if (iw < 0 || iw >= HW_) continue;
        s += x[((size_t)(nb * CI + c) * HW_ + ih) * HW_ + iw] *
             wt[(((size_t)oc * CI + c) * 3 + kh) * 3 + kw];
      }
    }
  out[idx] = s;
}

extern "C" void kernel_launch(void* const* d_in, const int* in_sizes, int n_in,
                              void* d_out, int out_size, void* d_ws, size_t ws_size,
                              hipStream_t stream) {
  const float* x    = (const float*)d_in[0];
  const float* wt   = (const float*)d_in[1];
  const float* bias = (const float*)d_in[2];
  float* out        = (float*)d_out;

  if (ws_size < XP_BYTES + WT_BYTES) {
    conv_naive<<<(NB * CO * 3136 + 255) / 256, 256, 0, stream>>>(x, wt, bias, out);
    return;
  }

  short* xp  = (short*)d_ws;
  short* wbT = (short*)((char*)d_ws + XP_BYTES);

  pad_convert<<<NB * HP, 256, 0, stream>>>(x, xp, wt, wbT);
  conv_gemm<<<(MTOT / 256) * 2, 256, 0, stream>>>(xp, wbT, bias, out);
}

// Round 17
// 92.858 us; speedup vs baseline: 1.1263x; 1.1263x over previous
//
#include <hip/hip_runtime.h>
#include <cstdint>
#include <cstddef>

// ---------------- problem constants ----------------
#define NB    32          // batch
#define CI    128         // in channels
#define CO    256         // out channels
#define HW_   56          // spatial
#define HP    58          // padded spatial
#define KTOT  1152        // 128*9 reduction
#define NKT   36          // K-tiles of 32
#define MTOT  (NB * HW_ * HW_)   // 100352 output pixels
#define BM    224         // M-tile (14 x 16); 448 M-tiles exactly

static constexpr size_t XP_ELEMS = (size_t)NB * HP * HP * CI;   // 13,776,896
static constexpr size_t WT_ELEMS = (size_t)CO * KTOT;           // 294,912
static constexpr size_t XP_BYTES = XP_ELEMS * 2;
static constexpr size_t WT_BYTES = WT_ELEMS * 2;

typedef __attribute__((ext_vector_type(8))) short bf16x8;
typedef __attribute__((ext_vector_type(4))) float f32x4;

__device__ __forceinline__ short f32_to_bf16(float f) {
  uint32_t u = __float_as_uint(f);
  uint32_t r = (u + 0x7FFFu + ((u >> 16) & 1u)) >> 16;
  return (short)r;
}

typedef __attribute__((address_space(3))) void       lds_void;
typedef const __attribute__((address_space(1))) void gbl_void;

__device__ __forceinline__ void gload16(const void* g, void* l) {
  // dest = wave-uniform LDS base; HW writes lane's 16B at base + lane*16
  __builtin_amdgcn_global_load_lds((gbl_void*)g, (lds_void*)l, 16, 0, 0);
}

// ---- pre-pass: x NCHW f32 -> padded NHWC bf16; wt OIHW -> [o][kh][kw][c] bf16 ----
__global__ void pad_convert(const float* __restrict__ x, short* __restrict__ xp,
                            const float* __restrict__ wt, short* __restrict__ wbT) {
  __shared__ float lds[CI][57];
  const int blk = blockIdx.x;    // NB*HP = 1856
  const int hp  = blk % HP;
  const int nb  = blk / HP;
  const int tid = threadIdx.x;   // 256

  if (blk < 1152) {              // 1152*256 == WT_ELEMS (scalar per thread)
    int idx = blk * 256 + tid;
    int c  = idx & 127;
    int t  = idx >> 7;          // o*9 + kh*3 + kw
    int kw = t % 3;  int t2 = t / 3;
    int kh = t2 % 3; int o  = t2 / 3;
    wbT[idx] = f32_to_bf16(wt[(((size_t)o * CI + c) * 3 + kh) * 3 + kw]);
  }

  const bool interior = (hp >= 1 && hp <= HW_);
  if (interior) {
    const float* src = x + (size_t)nb * CI * HW_ * HW_ + (size_t)(hp - 1) * HW_;
    for (int t = tid; t < CI * HW_; t += 256) {
      int c = t / HW_, w = t - (t / HW_) * HW_;
      lds[c][w] = src[(size_t)c * HW_ * HW_ + w];
    }
  }
  __syncthreads();
  short* dst = xp + (size_t)(nb * HP + hp) * HP * CI;
  for (int t = tid; t < HP * CI / 4; t += 256) {
    const int wp = t >> 5;
    const int c4 = (t & 31) * 4;
    short4 s;
    if (interior && wp >= 1 && wp <= HW_) {
      s.x = f32_to_bf16(lds[c4 + 0][wp - 1]);
      s.y = f32_to_bf16(lds[c4 + 1][wp - 1]);
      s.z = f32_to_bf16(lds[c4 + 2][wp - 1]);
      s.w = f32_to_bf16(lds[c4 + 3][wp - 1]);
    } else {
      s.x = s.y = s.z = s.w = 0;
    }
    *(short4*)(dst + t * 4) = s;
  }
}

// scalar byte offset into an xp pixel row for K-tile u (tap + channel-quarter)
__device__ __forceinline__ int stage_aoff(int u) {
  const int tap = u >> 2;            // 0..8
  const int cq  = u & 3;             // channel quarter (32 ch)
  const int kh  = tap / 3, kw = tap - kh * 3;
  return ((kh * HP + kw) * CI + cq * 32) * 2;
}

// ---------------- main: implicit GEMM, 224x128 tile, BK=32, 4 waves ----------------
// FINAL (best-measured config; R12 = 92.89 us, R15 repro = 93.56 us):
// R4's proven structure -- counted vmcnt(6) ledger, 3 x 24KB LDS buffers
// (2 blocks/CU), both-sides zero-conflict swizzle, 16x16x32 MFMA -- with
// BM=224 balancing the scheduling tail (grid 896 / 512 slots, eff 0.875).
// Session elimination set (all measured): counted-vmcnt +18%; T2 swizzle +9%;
// fine-phasing x3 (regress/race); occupancy 1/2/3 blocks null; fence-halving
// null; tail-rebalance null (ratio-cancelled); B-direct x2 regress;
// 32x32x16 MFMA regress (5.4M bank conflicts under available swizzles).
// Plateau: 29-31% MfmaUtil / ~750 TF -- the 2-barrier structure's
// balanced-pipe limit at this conv shape (m103: 36% at 4096^3).
__global__ __launch_bounds__(256, 2) void conv_gemm(
    const short* __restrict__ xp, const short* __restrict__ wbT,
    const float* __restrict__ bias, float* __restrict__ out) {
  __shared__ __align__(16) char lds_[3 * 24576];

  const int tid = threadIdx.x;     // 256
  const int l   = tid & 63;
  const int wv  = tid >> 6;        // 0..3
  const int wm  = wv >> 1;         // 0..1  (m half: 112 rows)
  const int wn  = wv & 1;          // 0..1  (oc half: 64 cols)

  // grid 896 = 8 XCDs x 112; chunked bijective swizzle, nt inner (A reuse in L2)
  const int bid = blockIdx.x;
  const int lin = (bid & 7) * 112 + (bid >> 3);
  const int mt  = lin >> 1;        // 0..447
  const int nt  = lin & 1;

  // ---- staging source pointers (pre-swizzled per rule #21) ----
  const int pcs  = (((l & 3) ^ ((l >> 3) & 3)) << 4);
  const int srow = 16 * wv + (l >> 2);                 // 0..63 per gload group
  const char *aSrc0, *aSrc1, *aSrc2, *aSrc3;
  {
#pragma unroll
    for (int g = 0; g < 4; ++g) {
      int m  = mt * BM + 64 * g + srow;
      if (m >= MTOT) m = 0;            // clamp: garbage rows 224-255, never read
      int nb = m / 3136, hw = m - nb * 3136;
      int h = hw / HW_, w = hw - (hw / HW_) * HW_;
      const char* p = (const char*)xp + ((size_t)((nb * HP + h) * HP + w) * CI) * 2 + pcs;
      if (g == 0) aSrc0 = p; else if (g == 1) aSrc1 = p;
      else if (g == 2) aSrc2 = p; else aSrc3 = p;
    }
  }
  const char* bSrc0 = (const char*)wbT + (size_t)(nt * 128 +      srow) * KTOT * 2 + pcs;
  const char* bSrc1 = (const char*)wbT + (size_t)(nt * 128 + 64 + srow) * KTOT * 2 + pcs;

  // ---- frag read lane offsets (swizzled koff; 0 conflicts, 7 passing rounds) ----
  const int lm   = l & 15;
  const int koff = (((l >> 4) ^ ((l >> 1) & 3)) << 4);
  const int raOff = (wm * 112 + lm) * 64 + koff;   // + g*1024, g=0..6
  const int rbOff = (wn * 64 + lm) * 64 + koff;    // + h*1024 (B region +16384)

  char* B0 = lds_;
  char* B1 = lds_ + 24576;
  char* B2 = lds_ + 49152;

#define STAGE(U, BUF)                                                        \
  {                                                                          \
    const int ao_ = stage_aoff(U);                                           \
    const int bo_ = (U) * 64;                                                \
    gload16(aSrc0 + ao_, (BUF) +         wv * 1024);                         \
    gload16(aSrc1 + ao_, (BUF) +  4096 + wv * 1024);                         \
    gload16(aSrc2 + ao_, (BUF) +  8192 + wv * 1024);                         \
    gload16(aSrc3 + ao_, (BUF) + 12288 + wv * 1024);                         \
    gload16(bSrc0 + bo_, (BUF) + 16384 + wv * 1024);                         \
    gload16(bSrc1 + bo_, (BUF) + 20480 + wv * 1024);                         \
  }

  f32x4 acc[7][4];
#pragma unroll
  for (int g = 0; g < 7; ++g)
#pragma unroll
    for (int h = 0; h < 4; ++h) acc[g][h] = {0.f, 0.f, 0.f, 0.f};

  // ---- prologue: stage tiles 0,1; confirm tile 0 ----
  STAGE(0, B0)
  STAGE(1, B1)
  asm volatile("s_waitcnt vmcnt(6)" ::: "memory");   // tile 0 landed
  __builtin_amdgcn_s_barrier();
  __builtin_amdgcn_sched_barrier(0);

#define TILE_BODY(V, CUR, STG)                                               \
  {                                                                          \
    const int v_ = (V);                                                      \
    if (v_ + 2 < NKT) STAGE(v_ + 2, STG)                                     \
    bf16x8 af[7], bf[4];                                                     \
    _Pragma("unroll") for (int g = 0; g < 7; ++g)                            \
        af[g] = *(const bf16x8*)((CUR) + raOff + g * 1024);                  \
    _Pragma("unroll") for (int h = 0; h < 4; ++h)                            \
        bf[h] = *(const bf16x8*)((CUR) + 16384 + rbOff + h * 1024);          \
    __builtin_amdgcn_s_setprio(1);                                           \
    _Pragma("unroll") for (int g = 0; g < 7; ++g)                            \
      _Pragma("unroll") for (int h = 0; h < 4; ++h)                          \
        acc[g][h] = __builtin_amdgcn_mfma_f32_16x16x32_bf16(                 \
            bf[h], af[g], acc[g][h], 0, 0, 0);                               \
    __builtin_amdgcn_s_setprio(0);                                           \
    if (v_ < NKT - 1) {                                                      \
      if (v_ == NKT - 2) { asm volatile("s_waitcnt vmcnt(0)" ::: "memory"); }\
      else               { asm volatile("s_waitcnt vmcnt(6)" ::: "memory"); }\
      __builtin_amdgcn_s_barrier();                                          \
      __builtin_amdgcn_sched_barrier(0);                                     \
    }                                                                        \
  }

  for (int v3 = 0; v3 < NKT; v3 += 3) {
    TILE_BODY(v3 + 0, B0, B2)   // tile v reads buf v%3, stages v+2 into (v+2)%3
    TILE_BODY(v3 + 1, B1, B0)
    TILE_BODY(v3 + 2, B2, B1)
  }
#undef TILE_BODY
#undef STAGE

  // ---- epilogue: D rows = oc, cols = m (swapped operands) -> coalesced stores ----
  const int mBase = mt * BM + wm * 112 + lm;
  const int ocB   = nt * 128 + wn * 64 + (l >> 4) * 4;
  float bv[4][4];
#pragma unroll
  for (int h = 0; h < 4; ++h)
#pragma unroll
    for (int j = 0; j < 4; ++j) bv[h][j] = bias[ocB + h * 16 + j];
#pragma unroll
  for (int g = 0; g < 7; ++g) {
    const int m  = mBase + g * 16;
    const int nb = m / 3136;
    const int hw = m - nb * 3136;
    float* op = out + (size_t)nb * CO * 3136 + hw;
#pragma unroll
    for (int h = 0; h < 4; ++h) {
      const int oc = ocB + h * 16;
#pragma unroll
      for (int j = 0; j < 4; ++j)
        op[(size_t)(oc + j) * 3136] = acc[g][h][j] + bv[h][j];
    }
  }
}

// ---------------- fallback (ws too small): naive direct conv ----------------
__global__ void conv_naive(const float* __restrict__ x, const float* __restrict__ wt,
                           const float* __restrict__ bias, float* __restrict__ out) {
  const int idx = blockIdx.x * 256 + threadIdx.x;
  if (idx >= NB * CO * 3136) return;
  const int w  = idx % HW_;
  const int h  = (idx / HW_) % HW_;
  const int oc = (idx / 3136) % CO;
  const int nb = idx / (3136 * CO);
  float s = bias[oc];
  for (int c = 0; c < CI; ++c)
    for (int kh = 0; kh < 3; ++kh) {
      const int ih = h + kh - 1;
      if (ih < 0 || ih >= HW_) continue;
      for (int kw = 0; kw < 3; ++kw) {
        const int iw = w + kw - 1;
        if (iw < 0 || iw >= HW_) continue;
        s += x[((size_t)(nb * CI + c) * HW_ + ih) * HW_ + iw] *
             wt[(((size_t)oc * CI + c) * 3 + kh) * 3 + kw];
      }
    }
  out[idx] = s;
}

extern "C" void kernel_launch(void* const* d_in, const int* in_sizes, int n_in,
                              void* d_out, int out_size, void* d_ws, size_t ws_size,
                              hipStream_t stream) {
  const float* x    = (const float*)d_in[0];
  const float* wt   = (const float*)d_in[1];
  const float* bias = (const float*)d_in[2];
  float* out        = (float*)d_out;

  if (ws_size < XP_BYTES + WT_BYTES) {
    conv_naive<<<(NB * CO * 3136 + 255) / 256, 256, 0, stream>>>(x, wt, bias, out);
    return;
  }

  short* xp  = (short*)d_ws;
  short* wbT = (short*)((char*)d_ws + XP_BYTES);

  pad_convert<<<NB * HP, 256, 0, stream>>>(x, xp, wt, wbT);
  conv_gemm<<<(MTOT / BM) * 2, 256, 0, stream>>>(xp, wbT, bias, out);
}